// Round 2
// baseline (781.123 us; speedup 1.0000x reference)
//
#include <hip/hip_runtime.h>

// Problem constants (match reference setup_inputs / module constants)
#define EPS_F      1e-4f
#define GRID_RES_F 0.01f
#define ATOL_F     0.01f
#define RTOL_F     1e-5f

static constexpr int V = 1200;
static constexpr int E = 4800;
static constexpr int S = V + E;      // 6000 filtration points
static constexpr int P = 2500;
static constexpr int R = 3;

// Native vector type for nontemporal stores (HIP float4 is a class type,
// which __builtin_nontemporal_store rejects; this alias is layout-identical).
typedef float v4f __attribute__((ext_vector_type(4)));

// Output layout (flat fp32, return order):
//   bars0: [0, 7500)   bars1: [7500, 15000)
//   G0: (R,P,2S) at 15000   G1: follows   Gc0: (R,P,2)   Gc1: follows
static constexpr size_t G0_BASE      = 15000ull;
static constexpr size_t ROW_LEN      = 2ull * S;            // 12000 floats per G row
static constexpr size_t COMBO_STRIDE = (size_t)P * ROW_LEN; // 30,000,000 floats per (b,r) slab
static constexpr size_t G_ELEMS      = (size_t)R * COMBO_STRIDE; // 90,000,000
static constexpr size_t GC0_BASE     = G0_BASE + 2 * G_ELEMS;    // 180,015,000

// ---------------------------------------------------------------------------
// Kernel 1: build filtration table. filt[j] = (fx, fy, tol_x, tol_y)
// ---------------------------------------------------------------------------
__global__ void build_filt_kernel(const float* __restrict__ f_v,
                                  const int*   __restrict__ edges,
                                  float4*      __restrict__ filt) {
    int j = blockIdx.x * blockDim.x + threadIdx.x;
    if (j >= S) return;
    float fx, fy;
    if (j < V) {
        fx = f_v[2 * j];
        fy = f_v[2 * j + 1];
    } else {
        int e = j - V;
        int a = edges[2 * e];
        int b = edges[2 * e + 1];
        fx = __fadd_rn(fmaxf(f_v[2 * a],     f_v[2 * b]),     EPS_F);
        fy = __fadd_rn(fmaxf(f_v[2 * a + 1], f_v[2 * b + 1]), EPS_F);
    }
    // tol = ATOL + RTOL*|f| with NumPy per-op rounding (no fma contraction).
    float tolx = __fadd_rn(ATOL_F, __fmul_rn(RTOL_F, fabsf(fx)));
    float toly = __fadd_rn(ATOL_F, __fmul_rn(RTOL_F, fabsf(fy)));
    filt[j] = make_float4(fx, fy, tolx, toly);
}

// ---------------------------------------------------------------------------
// min_k |l[k] - f| ; comparing vs tol is bit-exact-equivalent to
// any_k(|l[k]-f| <= tol) — min/cmp involve no rounding. Subs keep ref rounding.
// (Field-proven: absmax 0.0 in earlier rounds.)
// ---------------------------------------------------------------------------
__device__ __forceinline__ float mindist(const float* l, float f) {
    float a = fabsf(__fsub_rn(l[0], f));
    float b = fabsf(__fsub_rn(l[1], f));
    float c = fabsf(__fsub_rn(l[2], f));
    float d = fabsf(__fsub_rn(l[3], f));
    float e = fabsf(__fsub_rn(l[4], f));
    return fminf(fminf(fminf(a, b), fminf(c, d)), e);  // -> v_min3 pairs
}

// Per-cell evaluation for one (b,r) combo; flag bits accumulate into 6-bit masks.
__device__ __forceinline__ void cell(const float4& f, float psum,
                                     const float* lxs, const float* lys,
                                     float& vx, float& vy, int bit,
                                     int& aux, int& alx, int& auy, int& aly) {
    float fsum = __fadd_rn(f.x, f.y);
    bool ab = fsum > psum, be = fsum < psum;
    float sg = ab ? 1.0f : (be ? -1.0f : 0.0f);
    bool cx = (mindist(lxs, f.x) <= f.z) && (f.y <= lys[4]);
    bool cy = (mindist(lys, f.y) <= f.w) && (f.x <= lxs[4]);
    vx = cx ? sg : 0.0f;   // vx = ux - lx == condx ? (above - below) : 0
    vy = cy ? sg : 0.0f;
    if (cx && ab) aux |= bit;
    if (cx && be) alx |= bit;
    if (cy && ab) auy |= bit;
    if (cy && be) aly |= bit;
}

// ---------------------------------------------------------------------------
// Kernel 2: ONE block per sample point p, computing ALL 6 (bar-set, r) rows.
//   - filt is read once per block (240 MB total vs 1.44 GB before: 6x cut)
//   - 2 cells/thread -> each combo store is one dense float4 per lane
//     (wave store = contiguous fully-covered 1 KB span, full cache lines)
//   - nontemporal stores: G is write-once, keep it from evicting filt in L2
// ---------------------------------------------------------------------------
__global__ __launch_bounds__(512) void grad_kernel(
        const float4* __restrict__ filt,
        const float*  __restrict__ bars0,
        const float*  __restrict__ bars1,
        const float*  __restrict__ sample_pts,
        float*        __restrict__ d_out) {
    const int p = blockIdx.x;   // 0..P-1

    const float px = sample_pts[2 * p];
    const float py = sample_pts[2 * p + 1];
    const float psum = __fadd_rn(px, py);

    // Per-combo scale factors; combo c = 3*b + r.
    float sv[6], s2v[6];
#pragma unroll
    for (int c = 0; c < 6; ++c) {
        const float* bar = (c < 3) ? bars0 : bars1;
        const int r = (c < 3) ? c : c - 3;
        const float s = __fadd_rn(bar[p * R + r], GRID_RES_F);
        sv[c]  = s;
        s2v[c] = __fmul_rn(2.0f, s);   // exact (x2)
    }

    float* gbase = d_out + G0_BASE + (size_t)p * ROW_LEN;

    __shared__ int shf[24];            // [0..5]=ux, [6..11]=lx, [12..17]=uy, [18..23]=ly
    if (threadIdx.x < 24) shf[threadIdx.x] = 0;
    __syncthreads();

    int aux = 0, alx = 0, auy = 0, aly = 0;   // 6-bit masks, bit c per combo

    // 2 cells per thread per iteration; 512 threads -> 1024 cells per sweep.
    int j = threadIdx.x * 2;
    float4 a0, a1;
    if (j < S) { a0 = filt[j]; a1 = filt[j + 1]; }
    while (j < S) {
        const int jn = j + 1024;
        float4 b0, b1;
        if (jn < S) {   // prefetch next iteration's cells before compute/store
            b0 = filt[jn]; b1 = filt[jn + 1];
        }
#pragma unroll
        for (int c = 0; c < 6; ++c) {
            const float s = sv[c], s2 = s2v[c];
            // Reference rounding: line = fl(fl(shift*s) + p); shift*s exact for +-1,+-2.
            float lxs[5], lys[5];
            lxs[0] = __fadd_rn(-s2, px); lxs[1] = __fadd_rn(-s, px); lxs[2] = px;
            lxs[3] = __fadd_rn( s, px);  lxs[4] = __fadd_rn( s2, px);
            lys[0] = __fadd_rn(-s2, py); lys[1] = __fadd_rn(-s, py); lys[2] = py;
            lys[3] = __fadd_rn( s, py);  lys[4] = __fadd_rn( s2, py);
            const int bit = 1 << c;
            v4f o;
            float ox, oy, oz, ow;
            cell(a0, psum, lxs, lys, ox, oy, bit, aux, alx, auy, aly);
            cell(a1, psum, lxs, lys, oz, ow, bit, aux, alx, auy, aly);
            o.x = ox; o.y = oy; o.z = oz; o.w = ow;
            __builtin_nontemporal_store(o,
                reinterpret_cast<v4f*>(gbase + c * COMBO_STRIDE + 2 * (size_t)j));
        }
        a0 = b0; a1 = b1;
        j = jn;
    }

    // Row-wide any() flags: benign-race shared writes (all writers store 1).
#pragma unroll
    for (int c = 0; c < 6; ++c) {
        if (aux & (1 << c)) shf[c]      = 1;
        if (alx & (1 << c)) shf[6 + c]  = 1;
        if (auy & (1 << c)) shf[12 + c] = 1;
        if (aly & (1 << c)) shf[18 + c] = 1;
    }
    __syncthreads();

    if (threadIdx.x < 6) {
        const int c = threadIdx.x;
        float cx = shf[c]      ? -1.0f : (shf[6 + c]  ? 1.0f : 0.0f);
        float cy = shf[12 + c] ? -1.0f : (shf[18 + c] ? 1.0f : 0.0f);
        // Gc(b,r,p,2): GC0_BASE + b*R*P*2 + (r*P+p)*2 == GC0_BASE + c*5000 + 2p
        size_t gc = GC0_BASE + (size_t)c * ((size_t)P * 2) + (size_t)p * 2;
        d_out[gc]     = cx;
        d_out[gc + 1] = cy;
    }
}

// ---------------------------------------------------------------------------
extern "C" void kernel_launch(void* const* d_in, const int* in_sizes, int n_in,
                              void* d_out, int out_size, void* d_ws, size_t ws_size,
                              hipStream_t stream) {
    const float* f_v        = (const float*)d_in[0];
    const int*   edges      = (const int*)d_in[1];
    const float* bars0      = (const float*)d_in[2];
    const float* bars1      = (const float*)d_in[3];
    const float* sample_pts = (const float*)d_in[4];
    float* out = (float*)d_out;

    float4* filt = (float4*)d_ws;   // S * 16 B = 96 KB scratch

    // bars0 / bars1 pass through to output.
    (void)hipMemcpyAsync(out,         bars0, (size_t)P * R * sizeof(float),
                         hipMemcpyDeviceToDevice, stream);
    (void)hipMemcpyAsync(out + P * R, bars1, (size_t)P * R * sizeof(float),
                         hipMemcpyDeviceToDevice, stream);

    build_filt_kernel<<<(S + 255) / 256, 256, 0, stream>>>(f_v, edges, filt);

    grad_kernel<<<dim3(P), 512, 0, stream>>>(filt, bars0, bars1, sample_pts, out);
}

// Round 4
// 733.101 us; speedup vs baseline: 1.0655x; 1.0655x over previous
//
#include <hip/hip_runtime.h>

// Problem constants (match reference setup_inputs / module constants)
#define EPS_F      1e-4f
#define GRID_RES_F 0.01f
#define ATOL_F     0.01f
#define RTOL_F     1e-5f

static constexpr int V = 1200;
static constexpr int E = 4800;
static constexpr int S = V + E;      // 6000 filtration points
static constexpr int P = 2500;
static constexpr int R = 3;
static constexpr int PB = 4;         // p's per block: 4*48KB = 192KB sequential stream

// Output layout (flat fp32, return order):
//   bars0: [0, 7500)   bars1: [7500, 15000)
//   G0: (R,P,2S) at 15000   G1: follows   Gc0: (R,P,2)   Gc1: follows
static constexpr size_t G0_BASE  = 15000ull;
static constexpr size_t ROW_LEN  = 2ull * S;                 // 12000 floats per G row
static constexpr size_t G_ELEMS  = (size_t)R * P * ROW_LEN;  // 90,000,000
static constexpr size_t GC0_BASE = G0_BASE + 2 * G_ELEMS;    // 180,015,000

// ---------------------------------------------------------------------------
// Kernel 1: build filtration table. filt[j] = (fx, fy, tol_x, tol_y)
// ---------------------------------------------------------------------------
__global__ void build_filt_kernel(const float* __restrict__ f_v,
                                  const int*   __restrict__ edges,
                                  float4*      __restrict__ filt) {
    int j = blockIdx.x * blockDim.x + threadIdx.x;
    if (j >= S) return;
    float fx, fy;
    if (j < V) {
        fx = f_v[2 * j];
        fy = f_v[2 * j + 1];
    } else {
        int e = j - V;
        int a = edges[2 * e];
        int b = edges[2 * e + 1];
        fx = __fadd_rn(fmaxf(f_v[2 * a],     f_v[2 * b]),     EPS_F);
        fy = __fadd_rn(fmaxf(f_v[2 * a + 1], f_v[2 * b + 1]), EPS_F);
    }
    // tol = ATOL + RTOL*|f| with NumPy per-op rounding (no fma contraction).
    float tolx = __fadd_rn(ATOL_F, __fmul_rn(RTOL_F, fabsf(fx)));
    float toly = __fadd_rn(ATOL_F, __fmul_rn(RTOL_F, fabsf(fy)));
    filt[j] = make_float4(fx, fy, tolx, toly);
}

// ---------------------------------------------------------------------------
// min_k |l[k] - f| ; comparing vs tol is bit-exact-equivalent to
// any_k(|l[k]-f| <= tol) — min/cmp involve no rounding. Subs keep ref rounding.
// (Field-proven: absmax 0.0.)
// ---------------------------------------------------------------------------
__device__ __forceinline__ float mindist(const float* l, float f) {
    float a = fabsf(__fsub_rn(l[0], f));
    float b = fabsf(__fsub_rn(l[1], f));
    float c = fabsf(__fsub_rn(l[2], f));
    float d = fabsf(__fsub_rn(l[3], f));
    float e = fabsf(__fsub_rn(l[4], f));
    return fminf(fminf(fminf(a, b), fminf(c, d)), e);  // -> v_min3 pairs
}

__device__ __forceinline__ void cell(const float4& f, float psum,
                                     const float* lxs, const float* lys,
                                     float& vx, float& vy,
                                     int& aux, int& alx, int& auy, int& aly) {
    float fsum = __fadd_rn(f.x, f.y);
    bool ab = fsum > psum, be = fsum < psum;
    float sg = ab ? 1.0f : (be ? -1.0f : 0.0f);
    bool cx = (mindist(lxs, f.x) <= f.z) && (f.y <= lys[4]);
    bool cy = (mindist(lys, f.y) <= f.w) && (f.x <= lxs[4]);
    vx = cx ? sg : 0.0f;   // vx = ux - lx == condx ? (above - below) : 0
    vy = cy ? sg : 0.0f;
    aux |= (int)(cx && ab); alx |= (int)(cx && be);
    auy |= (int)(cy && ab); aly |= (int)(cy && be);
}

// ---------------------------------------------------------------------------
// Kernel 2: one block per (bar-set, r, p-batch). Inner loop IDENTICAL to the
// 726us R1 structure (4 cells/thread, register prefetch, regular stores).
// One change: each block sweeps PB=4 consecutive p's, so its G writes form a
// single 192KB sequential stream (4 adjacent rows) instead of 48KB — tests
// the store-stream-locality theory from the round-2 post-mortem. filt loads
// for p>0 re-hit L1/L2. Flags via per-wave __any, no reset race.
// ---------------------------------------------------------------------------
__global__ __launch_bounds__(256) void grad_kernel(
        const float4* __restrict__ filt,
        const float*  __restrict__ bars0,
        const float*  __restrict__ bars1,
        const float*  __restrict__ sample_pts,
        float*        __restrict__ d_out) {
    const int r = blockIdx.y;   // 0..R-1
    const int b = blockIdx.z;   // 0..1
    const float* bar = (b == 0) ? bars0 : bars1;
    const int p0 = blockIdx.x * PB;   // P == 625*4, no tail

    __shared__ int shw[4][4];   // [wave][flag]: ux, lx, uy, ly

    for (int pp = 0; pp < PB; ++pp) {
        const int p = p0 + pp;

        const float px = sample_pts[2 * p];
        const float py = sample_pts[2 * p + 1];
        const float psum = __fadd_rn(px, py);
        const float s  = __fadd_rn(bar[p * R + r], GRID_RES_F);
        const float s2 = __fmul_rn(2.0f, s);   // exact (x2)

        float lxs[5], lys[5];
        lxs[0] = __fadd_rn(-s2, px); lxs[1] = __fadd_rn(-s, px); lxs[2] = px;
        lxs[3] = __fadd_rn( s, px);  lxs[4] = __fadd_rn(s2, px);
        lys[0] = __fadd_rn(-s2, py); lys[1] = __fadd_rn(-s, py); lys[2] = py;
        lys[3] = __fadd_rn( s, py);  lys[4] = __fadd_rn(s2, py);

        float* Grow = d_out + G0_BASE + (size_t)b * G_ELEMS
                            + ((size_t)(r * P + p)) * ROW_LEN;

        int aux = 0, alx = 0, auy = 0, aly = 0;

        // 4 cells per thread per iteration; stride 1024 cells per block sweep.
        int j = threadIdx.x * 4;
        float4 a0, a1, a2, a3;
        if (j < S) { a0 = filt[j]; a1 = filt[j+1]; a2 = filt[j+2]; a3 = filt[j+3]; }
        while (j < S) {
            const int jn = j + 1024;
            float4 b0, b1, b2, b3;
            if (jn < S) {  // prefetch next iteration's cells before compute/store
                b0 = filt[jn]; b1 = filt[jn+1]; b2 = filt[jn+2]; b3 = filt[jn+3];
            }
            float4 o0, o1;
            cell(a0, psum, lxs, lys, o0.x, o0.y, aux, alx, auy, aly);
            cell(a1, psum, lxs, lys, o0.z, o0.w, aux, alx, auy, aly);
            cell(a2, psum, lxs, lys, o1.x, o1.y, aux, alx, auy, aly);
            cell(a3, psum, lxs, lys, o1.z, o1.w, aux, alx, auy, aly);
            float4* dst = reinterpret_cast<float4*>(Grow + 2 * j);
            dst[0] = o0;
            dst[1] = o1;
            a0 = b0; a1 = b1; a2 = b2; a3 = b3;
            j = jn;
        }

        // Block-wide any(): per-wave __any, lane 0 publishes, thread 0 combines.
        const int lane = threadIdx.x & 63;
        const int wid  = threadIdx.x >> 6;
        int f0 = __any(aux), f1 = __any(alx), f2 = __any(auy), f3 = __any(aly);
        if (lane == 0) {
            shw[wid][0] = f0; shw[wid][1] = f1; shw[wid][2] = f2; shw[wid][3] = f3;
        }
        __syncthreads();
        if (threadIdx.x == 0) {
            int ux = shw[0][0] | shw[1][0] | shw[2][0] | shw[3][0];
            int lx = shw[0][1] | shw[1][1] | shw[2][1] | shw[3][1];
            int uy = shw[0][2] | shw[1][2] | shw[2][2] | shw[3][2];
            int ly = shw[0][3] | shw[1][3] | shw[2][3] | shw[3][3];
            float cx = ux ? -1.0f : (lx ? 1.0f : 0.0f);
            float cy = uy ? -1.0f : (ly ? 1.0f : 0.0f);
            size_t gc = GC0_BASE + (size_t)b * ((size_t)R * P * 2)
                                 + ((size_t)(r * P + p)) * 2;
            d_out[gc]     = cx;
            d_out[gc + 1] = cy;
        }
        __syncthreads();   // shw stable before next p overwrites it
    }
}

// ---------------------------------------------------------------------------
extern "C" void kernel_launch(void* const* d_in, const int* in_sizes, int n_in,
                              void* d_out, int out_size, void* d_ws, size_t ws_size,
                              hipStream_t stream) {
    const float* f_v        = (const float*)d_in[0];
    const int*   edges      = (const int*)d_in[1];
    const float* bars0      = (const float*)d_in[2];
    const float* bars1      = (const float*)d_in[3];
    const float* sample_pts = (const float*)d_in[4];
    float* out = (float*)d_out;

    float4* filt = (float4*)d_ws;   // S * 16 B = 96 KB scratch

    // bars0 / bars1 pass through to output.
    (void)hipMemcpyAsync(out,         bars0, (size_t)P * R * sizeof(float),
                         hipMemcpyDeviceToDevice, stream);
    (void)hipMemcpyAsync(out + P * R, bars1, (size_t)P * R * sizeof(float),
                         hipMemcpyDeviceToDevice, stream);

    build_filt_kernel<<<(S + 255) / 256, 256, 0, stream>>>(f_v, edges, filt);

    grad_kernel<<<dim3(P / PB, R, 2), 256, 0, stream>>>(filt, bars0, bars1,
                                                        sample_pts, out);
}